// Round 6
// baseline (550.728 us; speedup 1.0000x reference)
//
#include <hip/hip_runtime.h>
#include <math.h>

typedef _Float16 f16x8 __attribute__((ext_vector_type(8)));
typedef _Float16 f16x4 __attribute__((ext_vector_type(4)));
typedef float    f32x4 __attribute__((ext_vector_type(4)));

#define B_TOT 2048
#define LSEQ  512
#define NS    16          // samples per group (MFMA N)
#define NG    2           // independent groups per workgroup (ILP interleave)
#define HS    72          // f16 per sample row of Hh (144 B)
#define LOG2E 1.44269504088896f
#define LN2   0.69314718055995f

#define MFMA16(A, B, C) __builtin_amdgcn_mfma_f32_16x16x32_f16((A), (B), (C), 0, 0, 0)

__global__ __launch_bounds__(256, 1)
void lstm_ilp2_kernel(const int* __restrict__ s,
                      const float* __restrict__ W0, const float* __restrict__ b0,
                      const float* __restrict__ Wi, const float* __restrict__ Wh,
                      const float* __restrict__ bh, const float* __restrict__ Wa,
                      const float* __restrict__ ba, const float* __restrict__ Wp,
                      const float* __restrict__ bp, float* __restrict__ out)
{
    const int tid  = threadIdx.x;
    const int w    = tid >> 6;     // wave 0..3: feature block 16w..16w+15 (all gates)
    const int lane = tid & 63;
    const int n    = lane & 15;    // sample within group
    const int q    = lane >> 4;
    const int b0s  = blockIdx.x * (NS * NG);

    __shared__ __align__(16) _Float16 Hh[2][NG][NS * HS];
    __shared__ unsigned short TOKB[NG][LSEQ + 2];
    __shared__ unsigned char  SRAW[NG * NS][LSEQ];
    __shared__ _Float16 DBUF[NG][LSEQ][NS];     // raw logit-diffs (f16), post-processed
    __shared__ float PART[NG][8][NS];

    // ---- stage tokens (coalesced in t) ----
    for (int i = tid; i < NG * NS * LSEQ; i += 256)
        SRAW[i >> 9][i & 511] = (unsigned char)s[(b0s + (i >> 9)) * LSEQ + (i & 511)];
    __syncthreads();
    for (int u = tid; u <= LSEQ; u += 256) {
        #pragma unroll
        for (int g = 0; g < NG; ++g) {
            unsigned int mask = 0;
            if (u >= 1) {
                #pragma unroll
                for (int m = 0; m < NS; ++m)
                    mask |= ((unsigned int)SRAW[g * NS + m][u - 1]) << m;
            }
            TOKB[g][u] = (unsigned short)mask;
        }
    }

    // ---- A-frags: scaled Wh^T (shared across groups) ----
    f16x8 awh[4][2];
    #pragma unroll
    for (int gg = 0; gg < 4; ++gg) {
        const float sc  = (gg == 2) ? (2.0f * LOG2E) : (-LOG2E);
        const int   col = 64 * gg + 16 * w + n;
        #pragma unroll
        for (int c = 0; c < 2; ++c)
            #pragma unroll
            for (int j = 0; j < 8; ++j)
                awh[gg][c][j] = (_Float16)(Wh[(32 * c + 8 * q + j) * 256 + col] * sc);
    }

    // ---- d-GEMM A-frag: row 0 = Wa[:,1]-Wa[:,0] ----
    f16x8 awd[2];
    #pragma unroll
    for (int c = 0; c < 2; ++c)
        #pragma unroll
        for (int j = 0; j < 8; ++j) {
            int k = 32 * c + 8 * q + j;
            awd[c][j] = (_Float16)((n == 0) ? (Wa[2 * k + 1] - Wa[2 * k]) : 0.0f);
        }
    const float dba = ba[1] - ba[0];

    // ---- p0/dp (scaled), shared across groups ----
    float p0v[4][4], dpv[4][4];
    {
        float a0[4][4], a1[4][4];
        #pragma unroll
        for (int gg = 0; gg < 4; ++gg)
            #pragma unroll
            for (int r = 0; r < 4; ++r) {
                float bb = bh[64 * gg + 16 * w + 4 * q + r];
                a0[gg][r] = bb; a1[gg][r] = bb;
            }
        for (int f = 0; f < 64; ++f) {
            float wb0 = W0[f]      + b0[f];
            float wb1 = W0[64 + f] + b0[f];
            #pragma unroll
            for (int gg = 0; gg < 4; ++gg) {
                const float4 wi4 = *(const float4*)&Wi[f * 256 + 64 * gg + 16 * w + 4 * q];
                #pragma unroll
                for (int r = 0; r < 4; ++r) {
                    float wi = (&wi4.x)[r];
                    a0[gg][r] = fmaf(wb0, wi, a0[gg][r]);
                    a1[gg][r] = fmaf(wb1, wi, a1[gg][r]);
                }
            }
        }
        #pragma unroll
        for (int gg = 0; gg < 4; ++gg) {
            const float sc = (gg == 2) ? (2.0f * LOG2E) : (-LOG2E);
            #pragma unroll
            for (int r = 0; r < 4; ++r) {
                p0v[gg][r] = a0[gg][r] * sc;
                dpv[gg][r] = (a1[gg][r] - a0[gg][r]) * sc;
            }
        }
    }

    __syncthreads();   // TOKB ready

    // ---- per-group state ----
    float h4[NG][4] = {}, c4[NG][4] = {};
    f32x4 ci[NG][4];
    #pragma unroll
    for (int g = 0; g < NG; ++g)
        #pragma unroll
        for (int gg = 0; gg < 4; ++gg)
            ci[g][gg] = (f32x4){p0v[gg][0], p0v[gg][1], p0v[gg][2], p0v[gg][3]};

    #pragma unroll 1
    for (int v = 0; v <= LSEQ; ++v) {
        const int p = v & 1;

        // publish h_{v-1} for both groups
        #pragma unroll
        for (int g = 0; g < NG; ++g) {
            f16x4 hv;
            #pragma unroll
            for (int r = 0; r < 4; ++r) hv[r] = (_Float16)h4[g][r];
            *(f16x4*)&Hh[p][g][n * HS + 16 * w + 4 * q] = hv;
        }
        __syncthreads();

        // B-frags for both groups
        f16x8 bf0[NG], bf1[NG];
        #pragma unroll
        for (int g = 0; g < NG; ++g) {
            bf0[g] = *(const f16x8*)&Hh[p][g][n * HS + 8 * q];
            bf1[g] = *(const f16x8*)&Hh[p][g][n * HS + 32 + 8 * q];
        }

        unsigned int tokn[NG];
        #pragma unroll
        for (int g = 0; g < NG; ++g)
            tokn[g] = (v < LSEQ) ? (unsigned int)TOKB[g][v + 1] : 0u;

        // gates GEMMs, both groups (independent chains — interleave fills latency)
        f32x4 acc[NG][4];
        #pragma unroll
        for (int g = 0; g < NG; ++g) {
            acc[g][0] = MFMA16(awh[0][0], bf0[g], ci[g][0]);
            acc[g][1] = MFMA16(awh[1][0], bf0[g], ci[g][1]);
            acc[g][2] = MFMA16(awh[2][0], bf0[g], ci[g][2]);
            acc[g][3] = MFMA16(awh[3][0], bf0[g], ci[g][3]);
            acc[g][0] = MFMA16(awh[0][1], bf1[g], acc[g][0]);
            acc[g][1] = MFMA16(awh[1][1], bf1[g], acc[g][1]);
            acc[g][2] = MFMA16(awh[2][1], bf1[g], acc[g][2]);
            acc[g][3] = MFMA16(awh[3][1], bf1[g], acc[g][3]);
        }

        // rotating wave: raw logit-diff d for step v-1, both groups; defer softplus
        if (v >= 1 && w == (v & 3)) {
            #pragma unroll
            for (int g = 0; g < NG; ++g) {
                f32x4 da = (f32x4){dba, dba, dba, dba};
                da = MFMA16(awd[0], bf0[g], da);
                da = MFMA16(awd[1], bf1[g], da);
                if (lane < 16) DBUF[g][v - 1][n] = (_Float16)da[0];
            }
        }

        // C-init for next iter
        #pragma unroll
        for (int g = 0; g < NG; ++g) {
            const float sel = (float)((tokn[g] >> n) & 1u);
            #pragma unroll
            for (int gg = 0; gg < 4; ++gg)
                #pragma unroll
                for (int r = 0; r < 4; ++r)
                    ci[g][gg][r] = fmaf(sel, dpv[gg][r], p0v[gg][r]);
        }

        // activations, both groups
        #pragma unroll
        for (int g = 0; g < NG; ++g)
            #pragma unroll
            for (int r = 0; r < 4; ++r) {
                float ei = __builtin_amdgcn_exp2f(acc[g][0][r]);               // e^{-i}
                float ef = __builtin_amdgcn_exp2f(acc[g][1][r]);               // e^{-f}
                float eg = __builtin_amdgcn_exp2f(fminf(acc[g][2][r], 60.f));  // e^{2g}
                float eo = __builtin_amdgcn_exp2f(acc[g][3][r]);               // e^{-o}
                float Rf  = __builtin_amdgcn_rcpf(1.0f + ef);
                float Rig = __builtin_amdgcn_rcpf((1.0f + ei) * (eg + 1.0f));
                float cn  = fmaf(c4[g][r], Rf, (eg - 1.0f) * Rig);
                c4[g][r] = cn;
                float ec = __builtin_amdgcn_exp2f(fminf(cn * (2.0f * LOG2E), 60.f));
                float Ro = __builtin_amdgcn_rcpf((1.0f + eo) * (ec + 1.0f));
                h4[g][r] = (ec - 1.0f) * Ro;
            }
    }

    // ---- tail: publish h_512 ----
    #pragma unroll
    for (int g = 0; g < NG; ++g) {
        f16x4 hv;
        #pragma unroll
        for (int r = 0; r < 4; ++r) hv[r] = (_Float16)h4[g][r];
        *(f16x4*)&Hh[1][g][n * HS + 16 * w + 4 * q] = hv;
    }
    __syncthreads();

    // ---- amp post-pass: softplus over DBUF; 64 terms per thread ----
    {
        const int g  = tid >> 7;            // 0..1
        const int nn = tid & 15;
        const int ch = (tid >> 4) & 7;      // 8 chunks of 64 steps
        float a = 0.0f;
        #pragma unroll 4
        for (int k = 0; k < 64; ++k) {
            int t = ch * 64 + k;
            float d = (float)DBUF[g][t][nn];
            float x = SRAW[g * NS + nn][t] ? -d : d;
            float e = __builtin_amdgcn_exp2f(-fabsf(x) * LOG2E);
            a += fmaxf(x, 0.0f) + __builtin_amdgcn_logf(1.0f + e) * LN2;
        }
        PART[g][ch][nn] = a;
    }
    __syncthreads();

    if (tid < 16 * NG) {
        const int g = tid >> 4, nn = tid & 15;
        float ssum = 0.0f;
        #pragma unroll
        for (int c = 0; c < 8; ++c) ssum += PART[g][c][nn];
        out[b0s + g * NS + nn] = -0.5f * ssum;      // planar real
    }

    // ---- phase: wave g handles group g ----
    if (w < NG) {
        const _Float16* hp = &Hh[1][w][n * HS + 16 * q];
        f16x8 h0 = *(const f16x8*)hp;
        f16x8 h1 = *(const f16x8*)(hp + 8);
        float ph = 0.0f;
        #pragma unroll
        for (int j = 0; j < 8; ++j)
            ph = fmaf((float)h0[j], Wp[16 * q + j],
                 fmaf((float)h1[j], Wp[16 * q + j + 8], ph));
        ph += __shfl_xor(ph, 16, 64);
        ph += __shfl_xor(ph, 32, 64);
        if (q == 0) out[B_TOT + b0s + w * NS + n] = ph + bp[0];   // planar imag
    }
}

extern "C" void kernel_launch(void* const* d_in, const int* in_sizes, int n_in,
                              void* d_out, int out_size, void* d_ws, size_t ws_size,
                              hipStream_t stream) {
    const int*   s  = (const int*)  d_in[0];
    const float* W0 = (const float*)d_in[1];
    const float* b0 = (const float*)d_in[2];
    const float* Wi = (const float*)d_in[3];
    const float* Wh = (const float*)d_in[4];
    const float* bh = (const float*)d_in[5];
    const float* Wa = (const float*)d_in[6];
    const float* ba = (const float*)d_in[7];
    const float* Wp = (const float*)d_in[8];
    const float* bp = (const float*)d_in[9];
    float* out = (float*)d_out;

    dim3 grid(B_TOT / (NS * NG));   // 64 workgroups; latency-bound
    dim3 block(256);
    lstm_ilp2_kernel<<<grid, block, 0, stream>>>(s, W0, b0, Wi, Wh, bh,
                                                 Wa, ba, Wp, bp, out);
}

// Round 7
// 431.920 us; speedup vs baseline: 1.2751x; 1.2751x over previous
//
#include <hip/hip_runtime.h>
#include <math.h>

typedef _Float16 f16x8 __attribute__((ext_vector_type(8)));
typedef _Float16 f16x4 __attribute__((ext_vector_type(4)));
typedef float    f32x4 __attribute__((ext_vector_type(4)));

#define B_TOT 2048
#define LSEQ  512
#define NS    16          // samples per group (MFMA N)
#define NG    2           // groups per workgroup, one per 4-wave set (TLP, not ILP)
#define HS    88          // f16 per sample row of Hh (176 B)
#define LOG2E 1.44269504088896f
#define LN2   0.69314718055995f

#define MFMA16(A, B, C) __builtin_amdgcn_mfma_f32_16x16x32_f16((A), (B), (C), 0, 0, 0)

__global__ __launch_bounds__(512, 1)
void lstm_tlp_kernel(const int* __restrict__ s,
                     const float* __restrict__ W0, const float* __restrict__ b0,
                     const float* __restrict__ Wi, const float* __restrict__ Wh,
                     const float* __restrict__ bh, const float* __restrict__ Wa,
                     const float* __restrict__ ba, const float* __restrict__ Wp,
                     const float* __restrict__ bp, float* __restrict__ out)
{
    const int tid  = threadIdx.x;
    const int wave = tid >> 6;       // 0..7
    const int grp  = wave >> 2;      // 0..1 — independent sample group per 4-wave set
    const int w    = wave & 3;       // feature block 16w..16w+15 within the group
    const int lane = tid & 63;
    const int n    = lane & 15;      // sample within group
    const int q    = lane >> 4;
    const int b0s  = blockIdx.x * (NS * NG);

    __shared__ __align__(16) _Float16 Hh[2][NG][NS * HS];   // 11264 B
    __shared__ unsigned short TOKB[NG][LSEQ + 2];           //  2056 B
    __shared__ unsigned char  SRAW[NG * NS][LSEQ];          // 16384 B
    __shared__ _Float16 DBUF[NG][LSEQ][NS];                 // 32768 B
    __shared__ float PART[NG][16][NS];                      //  2048 B

    // ---- stage tokens (coalesced in t) ----
    for (int i = tid; i < NG * NS * LSEQ; i += 512)
        SRAW[i >> 9][i & 511] = (unsigned char)s[(b0s + (i >> 9)) * LSEQ + (i & 511)];
    __syncthreads();
    for (int u = tid; u <= LSEQ; u += 512) {
        #pragma unroll
        for (int g = 0; g < NG; ++g) {
            unsigned int mask = 0;
            if (u >= 1) {
                #pragma unroll
                for (int m = 0; m < NS; ++m)
                    mask |= ((unsigned int)SRAW[g * NS + m][u - 1]) << m;
            }
            TOKB[g][u] = (unsigned short)mask;
        }
    }

    // ---- A-frags: scaled Wh^T (per wave; depends only on w) ----
    f16x8 awh[4][2];
    #pragma unroll
    for (int gg = 0; gg < 4; ++gg) {
        const float sc  = (gg == 2) ? (2.0f * LOG2E) : (-LOG2E);
        const int   col = 64 * gg + 16 * w + n;
        #pragma unroll
        for (int c = 0; c < 2; ++c)
            #pragma unroll
            for (int j = 0; j < 8; ++j)
                awh[gg][c][j] = (_Float16)(Wh[(32 * c + 8 * q + j) * 256 + col] * sc);
    }

    // ---- d-GEMM A-frag: row 0 = Wa[:,1]-Wa[:,0] ----
    f16x8 awd[2];
    #pragma unroll
    for (int c = 0; c < 2; ++c)
        #pragma unroll
        for (int j = 0; j < 8; ++j) {
            int k = 32 * c + 8 * q + j;
            awd[c][j] = (_Float16)((n == 0) ? (Wa[2 * k + 1] - Wa[2 * k]) : 0.0f);
        }
    const float dba = ba[1] - ba[0];

    // ---- p0/dp (scaled) ----
    float p0v[4][4], dpv[4][4];
    {
        float a0[4][4], a1[4][4];
        #pragma unroll
        for (int gg = 0; gg < 4; ++gg)
            #pragma unroll
            for (int r = 0; r < 4; ++r) {
                float bb = bh[64 * gg + 16 * w + 4 * q + r];
                a0[gg][r] = bb; a1[gg][r] = bb;
            }
        for (int f = 0; f < 64; ++f) {
            float wb0 = W0[f]      + b0[f];
            float wb1 = W0[64 + f] + b0[f];
            #pragma unroll
            for (int gg = 0; gg < 4; ++gg) {
                const float4 wi4 = *(const float4*)&Wi[f * 256 + 64 * gg + 16 * w + 4 * q];
                #pragma unroll
                for (int r = 0; r < 4; ++r) {
                    float wi = (&wi4.x)[r];
                    a0[gg][r] = fmaf(wb0, wi, a0[gg][r]);
                    a1[gg][r] = fmaf(wb1, wi, a1[gg][r]);
                }
            }
        }
        #pragma unroll
        for (int gg = 0; gg < 4; ++gg) {
            const float sc = (gg == 2) ? (2.0f * LOG2E) : (-LOG2E);
            #pragma unroll
            for (int r = 0; r < 4; ++r) {
                p0v[gg][r] = a0[gg][r] * sc;
                dpv[gg][r] = (a1[gg][r] - a0[gg][r]) * sc;
            }
        }
    }

    __syncthreads();   // TOKB ready

    // ---- state: this wave's group only (TLP — no in-wave duplication) ----
    float h4[4] = {0, 0, 0, 0}, c4[4] = {0, 0, 0, 0};
    f32x4 ci[4];
    #pragma unroll
    for (int gg = 0; gg < 4; ++gg)
        ci[gg] = (f32x4){p0v[gg][0], p0v[gg][1], p0v[gg][2], p0v[gg][3]};

    #pragma unroll 1
    for (int v = 0; v <= LSEQ; ++v) {
        const int p = v & 1;

        // publish h_{v-1}
        f16x4 hv;
        #pragma unroll
        for (int r = 0; r < 4; ++r) hv[r] = (_Float16)h4[r];
        *(f16x4*)&Hh[p][grp][n * HS + 16 * w + 4 * q] = hv;
        __syncthreads();

        // B-frags of h_{v-1} (this group)
        f16x8 bf0 = *(const f16x8*)&Hh[p][grp][n * HS + 8 * q];
        f16x8 bf1 = *(const f16x8*)&Hh[p][grp][n * HS + 32 + 8 * q];

        const unsigned int tokm_next = (v < LSEQ) ? (unsigned int)TOKB[grp][v + 1] : 0u;

        // gates GEMM
        f32x4 acc0 = ci[0], acc1 = ci[1], acc2 = ci[2], acc3 = ci[3];
        acc0 = MFMA16(awh[0][0], bf0, acc0);
        acc1 = MFMA16(awh[1][0], bf0, acc1);
        acc2 = MFMA16(awh[2][0], bf0, acc2);
        acc3 = MFMA16(awh[3][0], bf0, acc3);
        acc0 = MFMA16(awh[0][1], bf1, acc0);
        acc1 = MFMA16(awh[1][1], bf1, acc1);
        acc2 = MFMA16(awh[2][1], bf1, acc2);
        acc3 = MFMA16(awh[3][1], bf1, acc3);

        // rotating wave within the group: raw logit-diff for step v-1
        if (v >= 1 && w == (v & 3)) {
            f32x4 da = (f32x4){dba, dba, dba, dba};
            da = MFMA16(awd[0], bf0, da);
            da = MFMA16(awd[1], bf1, da);
            if (lane < 16) DBUF[grp][v - 1][n] = (_Float16)da[0];
        }

        // C-init for next iter
        const float sel = (float)((tokm_next >> n) & 1u);
        #pragma unroll
        for (int gg = 0; gg < 4; ++gg)
            #pragma unroll
            for (int r = 0; r < 4; ++r)
                ci[gg][r] = fmaf(sel, dpv[gg][r], p0v[gg][r]);

        // activations
        #pragma unroll
        for (int r = 0; r < 4; ++r) {
            float ei = __builtin_amdgcn_exp2f(acc0[r]);               // e^{-i}
            float ef = __builtin_amdgcn_exp2f(acc1[r]);               // e^{-f}
            float eg = __builtin_amdgcn_exp2f(fminf(acc2[r], 60.f));  // e^{2g}
            float eo = __builtin_amdgcn_exp2f(acc3[r]);               // e^{-o}
            float Rf  = __builtin_amdgcn_rcpf(1.0f + ef);
            float Rig = __builtin_amdgcn_rcpf((1.0f + ei) * (eg + 1.0f));
            float cn  = fmaf(c4[r], Rf, (eg - 1.0f) * Rig);
            c4[r] = cn;
            float ec = __builtin_amdgcn_exp2f(fminf(cn * (2.0f * LOG2E), 60.f));
            float Ro = __builtin_amdgcn_rcpf((1.0f + eo) * (ec + 1.0f));
            h4[r] = (ec - 1.0f) * Ro;
        }
    }

    // ---- tail: publish h_512 ----
    {
        f16x4 hv;
        #pragma unroll
        for (int r = 0; r < 4; ++r) hv[r] = (_Float16)h4[r];
        *(f16x4*)&Hh[1][grp][n * HS + 16 * w + 4 * q] = hv;
    }
    __syncthreads();

    // ---- amp post-pass: 512 threads, 32 softplus terms each ----
    {
        const int g  = tid >> 8;            // 0..1
        const int nn = tid & 15;
        const int ch = (tid >> 4) & 15;     // 16 chunks of 32 steps
        float a = 0.0f;
        #pragma unroll 4
        for (int k = 0; k < 32; ++k) {
            int t = ch * 32 + k;
            float d = (float)DBUF[g][t][nn];
            float x = SRAW[g * NS + nn][t] ? -d : d;
            float e = __builtin_amdgcn_exp2f(-fabsf(x) * LOG2E);
            a += fmaxf(x, 0.0f) + __builtin_amdgcn_logf(1.0f + e) * LN2;
        }
        PART[g][ch][nn] = a;
    }
    __syncthreads();

    if (tid < 16 * NG) {
        const int g = tid >> 4, nn = tid & 15;
        float ssum = 0.0f;
        #pragma unroll
        for (int c = 0; c < 16; ++c) ssum += PART[g][c][nn];
        out[b0s + g * NS + nn] = -0.5f * ssum;      // planar real
    }

    // ---- phase: wave 0 of each group ----
    if (w == 0) {
        const _Float16* hp = &Hh[1][grp][n * HS + 16 * q];
        f16x8 h0 = *(const f16x8*)hp;
        f16x8 h1 = *(const f16x8*)(hp + 8);
        float ph = 0.0f;
        #pragma unroll
        for (int j = 0; j < 8; ++j)
            ph = fmaf((float)h0[j], Wp[16 * q + j],
                 fmaf((float)h1[j], Wp[16 * q + j + 8], ph));
        ph += __shfl_xor(ph, 16, 64);
        ph += __shfl_xor(ph, 32, 64);
        if (q == 0) out[B_TOT + b0s + grp * NS + n] = ph + bp[0];   // planar imag
    }
}

extern "C" void kernel_launch(void* const* d_in, const int* in_sizes, int n_in,
                              void* d_out, int out_size, void* d_ws, size_t ws_size,
                              hipStream_t stream) {
    const int*   s  = (const int*)  d_in[0];
    const float* W0 = (const float*)d_in[1];
    const float* b0 = (const float*)d_in[2];
    const float* Wi = (const float*)d_in[3];
    const float* Wh = (const float*)d_in[4];
    const float* bh = (const float*)d_in[5];
    const float* Wa = (const float*)d_in[6];
    const float* ba = (const float*)d_in[7];
    const float* Wp = (const float*)d_in[8];
    const float* bp = (const float*)d_in[9];
    float* out = (float*)d_out;

    dim3 grid(B_TOT / (NS * NG));   // 64 WGs × 512 threads: 2 waves/SIMD on 64 CUs
    dim3 block(512);
    lstm_tlp_kernel<<<grid, block, 0, stream>>>(s, W0, b0, Wi, Wh, bh,
                                                Wa, ba, Wp, bp, out);
}